// Round 8
// baseline (166.346 us; speedup 1.0000x reference)
//
#include <hip/hip_runtime.h>
#include <hip/hip_bf16.h>

// B=2, H=8, S=1024, D=64. Outputs: context [B,S,H*D] f32 then
// attention_weights [B,H,H,S,S] f32, concatenated flat in d_out.
#define B_ 2
#define H_ 8
#define S_ 1024
#define D_ 64
#define PLP 136            // strip row pitch in shorts (272 B, 16B-aligned rows)
#define STRIPH (16 * PLP)  // shorts per 16-row sub-strip (t-extent 128)

typedef short short8 __attribute__((ext_vector_type(8)));   // 8 x bf16 (4 VGPR)
typedef float f32x4 __attribute__((ext_vector_type(4)));    // mfma C/D

__device__ __forceinline__ unsigned int f2bf(float f) {
  union { float f; unsigned int u; } v; v.f = f;
  return (v.u + 0x7fffu + ((v.u >> 16) & 1u)) >> 16;        // RNE
}
__device__ __forceinline__ float bf2f(unsigned int bits) {
  union { unsigned int u; float f; } v; v.u = bits << 16;
  return v.f;
}
__device__ __forceinline__ unsigned int cvt_pk_bf16(float lo, float hi) {
  unsigned int r;
  asm("v_cvt_pk_bf16_f32 %0, %1, %2" : "=v"(r) : "v"(lo), "v"(hi));
  return r;
}

// Fused prologue: bid<1024 conv Q, <2048 conv K, else transpose V (64x64).
__global__ void prologue_kernel(const float* __restrict__ Q,
                                const float* __restrict__ K,
                                const float* __restrict__ V,
                                unsigned short* __restrict__ Qb,
                                unsigned short* __restrict__ Kb,
                                unsigned short* __restrict__ Vt) {
  __shared__ float tile[64][65];
  const int bid = blockIdx.x;
  if (bid < 2048) {
    const float* src = (bid < 1024) ? Q : K;
    unsigned short* dst = (bid < 1024) ? Qb : Kb;
    int idx = (bid & 1023) * 256 + threadIdx.x;      // n4 = 262144 exactly
    const float4 v = ((const float4*)src)[idx];
    unsigned int lo = f2bf(v.x) | (f2bf(v.y) << 16);
    unsigned int hi = f2bf(v.z) | (f2bf(v.w) << 16);
    ((uint2*)dst)[idx] = make_uint2(lo, hi);
    return;
  }
  const int tb = bid - 2048;                          // 256 transpose blocks
  int bh = tb >> 4;
  int t0 = (tb & 15) * 64;
  int tid = threadIdx.x;               // 256
  int cx = tid & 63, ry = tid >> 6;
  const float* src = V + ((size_t)bh * S_ + t0) * D_;
#pragma unroll
  for (int r = 0; r < 16; ++r) {
    int row = r * 4 + ry;
    tile[row][cx] = src[(size_t)row * D_ + cx];
  }
  __syncthreads();
  unsigned short* dst = Vt + (size_t)bh * D_ * S_ + t0;
#pragma unroll
  for (int r = 0; r < 16; ++r) {
    int d = r * 4 + ry;
    dst[(size_t)d * S_ + cx] = (unsigned short)f2bf(tile[cx][d]);
  }
}

// Block (512 thr = 8 waves) owns (b, i, 64-row s-block). Wave w owns
// t-EIGHTH [w*128, w*128+128) for ALL 64 rows (4 sixteen-row sub-strips
// A-D; halves h0 = {A,B} rows 0-31, h1 = {C,D} rows 32-63).
//
// Round-8: half-tile software pipeline so stores issue in EVERY slot.
// 17 slots: prologue pass1(j0,h0); then per j two slots:
//   slot A: pass1(j,h1)   || PV+store(j,h0)
//   slot B: pass1(j+1,h0) || PV+store(j,h1)   (j=7: dummy pass1 of (0,h0))
// pass-1 of one half writes strips A/B or C/D while the OTHER pair is
// read by PV/stores -> no strip conflict, no extra LDS. ssum parity =
// half index (natural double-buffer). One LDS-only barrier per slot;
// W-stores never vmcnt-drained. K/Vt fragments re-read once per half
// (L2-resident, ~1 us/j) -- the price for ~100% store-issue duty.
__global__ __launch_bounds__(512, 2) void attn_kernel(
    const unsigned short* __restrict__ Qb,   // [B,H,S,D] bf16
    const unsigned short* __restrict__ Kb,   // [B,H,S,D] bf16
    const unsigned short* __restrict__ Vt,   // [B,H,D,S] bf16
    float* __restrict__ w_out,               // [B,H,H,S,S] f32
    float* __restrict__ ctx_out)             // [B,S,H*D] f32
{
  const int tid  = threadIdx.x;
  const int w    = tid >> 6;       // wave 0..7 (t-eighth)
  const int lane = tid & 63;
  const int g = lane >> 4;         // lane group 0..3
  const int c = lane & 15;         // col-in-16
  // XCD-contiguous swizzle: each XCD gets 32 consecutive bids (same b).
  const int raw = blockIdx.x;                    // 256 = B*H*(S/64)
  const int bid = (raw & 7) * 32 + (raw >> 3);
  const int sb = bid & 15;
  const int i  = (bid >> 4) & 7;
  const int b  = bid >> 7;
  const int s0 = sb * 64;
  const int t0 = w * 128;

  __shared__ __align__(16) unsigned short pstrips[32 * STRIPH]; // 139264 B
  __shared__ float ssum[2][8][32];                              // half-parity
  unsigned short* stripA = pstrips + (4 * w) * STRIPH;
  unsigned short* stripB = stripA + STRIPH;
  unsigned short* stripC = stripB + STRIPH;
  unsigned short* stripD = stripC + STRIPH;

  // per-lane offsets for the two-row f32x4 W-store (lanes 0-31 row r,
  // lanes 32-63 row r+1; cols (lane&31)*4 .. +3 within the t-eighth)
  const int l5  = lane >> 5;
  const int l31 = lane & 31;
  const int soff = l5 * PLP + l31 * 4;   // strip offset (shorts)

  // Q as B-fragment: lane holds Q[s][d = g*8..g*8+7], sub-strips A..D =
  // rows s0+0..15, +16..31, +32..47, +48..63.
  const unsigned short* qrow =
      Qb + ((size_t)((b * H_ + i) * S_) + s0 + c) * D_ + g * 8;
  short8 qa0 = *(const short8*)(qrow);
  short8 qa1 = *(const short8*)(qrow + 32);
  short8 qb0 = *(const short8*)(qrow + 16 * D_);
  short8 qb1 = *(const short8*)(qrow + 16 * D_ + 32);
  short8 qc0 = *(const short8*)(qrow + 32 * D_);
  short8 qc1 = *(const short8*)(qrow + 32 * D_ + 32);
  short8 qd0 = *(const short8*)(qrow + 48 * D_);
  short8 qd1 = *(const short8*)(qrow + 48 * D_ + 32);

  f32x4 ctxA[4], ctxB[4], ctxC[4], ctxD[4];
#pragma unroll
  for (int nt = 0; nt < 4; ++nt) {
    ctxA[nt] = (f32x4){0.f, 0.f, 0.f, 0.f};
    ctxB[nt] = (f32x4){0.f, 0.f, 0.f, 0.f};
    ctxC[nt] = (f32x4){0.f, 0.f, 0.f, 0.f};
    ctxD[nt] = (f32x4){0.f, 0.f, 0.f, 0.f};
  }

  const float SC = 0.18033688011112042f;  // log2(e) / sqrt(D=64)

// ---- pass-1 piece for one 16-row sub-strip at K-slice tt ----
#define PASS1_SUB(KF0, KF1, QF0, QF1, RS, STRIPP, TT)                         \
  {                                                                           \
    f32x4 acc = (f32x4){0.f, 0.f, 0.f, 0.f};                                  \
    acc = __builtin_amdgcn_mfma_f32_16x16x32_bf16(KF0, QF0, acc, 0, 0, 0);    \
    acc = __builtin_amdgcn_mfma_f32_16x16x32_bf16(KF1, QF1, acc, 0, 0, 0);    \
    float e0 = exp2f(acc[0] * SC);                                            \
    float e1 = exp2f(acc[1] * SC);                                            \
    float e2 = exp2f(acc[2] * SC);                                            \
    float e3 = exp2f(acc[3] * SC);                                            \
    RS += (e0 + e1) + (e2 + e3);                                              \
    uint2 pk = make_uint2(cvt_pk_bf16(e0, e1), cvt_pk_bf16(e2, e3));          \
    *(uint2*)&STRIPP[c * PLP + (TT) * 16 + 4 * g] = pk;                       \
  }

// ---- PV + store chunk CH (t-chunk CH*32 for PV; 4 two-row stores) ----
#define PVS_CHUNK(CH, SV0, SV1, PV0, PV1, IQ0, IQ1, VB, WL)                   \
  {                                                                           \
    short8 pa0 = *(const short8*)&SV0[c * PLP + (CH) * 32 + g * 8];           \
    short8 pa1 = *(const short8*)&SV1[c * PLP + (CH) * 32 + g * 8];           \
    _Pragma("unroll")                                                         \
    for (int nt = 0; nt < 4; ++nt) {                                          \
      short8 vf = *(const short8*)((VB) + (size_t)nt * 16 * S_ + (CH) * 32);  \
      PV0[nt] = __builtin_amdgcn_mfma_f32_16x16x32_bf16(pa0, vf, PV0[nt], 0, 0, 0); \
      PV1[nt] = __builtin_amdgcn_mfma_f32_16x16x32_bf16(pa1, vf, PV1[nt], 0, 0, 0); \
    }                                                                         \
    const unsigned short* sh_ = ((CH) < 2) ? (SV0) : (SV1);                   \
    const float iqh_ = ((CH) < 2) ? (IQ0) : (IQ1);                            \
    _Pragma("unroll")                                                         \
    for (int q = 0; q < 4; ++q) {                                             \
      const int rr = ((CH) & 1) * 8 + 2 * q;                                  \
      float s0v = __uint_as_float(                                            \
          __builtin_amdgcn_readlane(__float_as_uint(iqh_), rr));              \
      float s1v = __uint_as_float(                                            \
          __builtin_amdgcn_readlane(__float_as_uint(iqh_), rr + 1));          \
      float iql = (lane & 32) ? s1v : s0v;                                    \
      uint2 pk = *(const uint2*)&sh_[rr * PLP + soff];                        \
      f32x4 ww;                                                               \
      ww[0] = bf2f(pk.x & 0xffffu) * iql;                                     \
      ww[1] = bf2f(pk.x >> 16)     * iql;                                     \
      ww[2] = bf2f(pk.y & 0xffffu) * iql;                                     \
      ww[3] = bf2f(pk.y >> 16)     * iql;                                     \
      __builtin_nontemporal_store(ww,                                         \
          (f32x4*)((WL) + (size_t)(((CH) < 2 ? 0 : 16) + rr) * S_));          \
    }                                                                         \
  }

#define ROWSUM(PAR, OFS)                                                      \
    (ssum[PAR][0][(OFS) + c] + ssum[PAR][1][(OFS) + c] +                      \
     ssum[PAR][2][(OFS) + c] + ssum[PAR][3][(OFS) + c] +                      \
     ssum[PAR][4][(OFS) + c] + ssum[PAR][5][(OFS) + c] +                      \
     ssum[PAR][6][(OFS) + c] + ssum[PAR][7][(OFS) + c])

#define CTX_SCALE(IQ, PV, CTX)                                                \
    {                                                                         \
      float r0 = __shfl(IQ, 4 * g + 0, 64);                                   \
      float r1 = __shfl(IQ, 4 * g + 1, 64);                                   \
      float r2 = __shfl(IQ, 4 * g + 2, 64);                                   \
      float r3 = __shfl(IQ, 4 * g + 3, 64);                                   \
      _Pragma("unroll")                                                       \
      for (int nt = 0; nt < 4; ++nt) {                                        \
        CTX[nt][0] += PV[nt][0] * r0;                                         \
        CTX[nt][1] += PV[nt][1] * r1;                                         \
        CTX[nt][2] += PV[nt][2] * r2;                                         \
        CTX[nt][3] += PV[nt][3] * r3;                                         \
      }                                                                       \
    }

// ---- one pipeline slot: pass1(JP, half with strips SP0/SP1, Q frags,
// ssum parity PARP) interleaved with PV+store of (JV, strips SV0/SV1,
// ctx CTX0/CTX1, parity PARV, row base ROWB). Barrier at end. ----
#define SLOT(JP, QP00, QP01, QP10, QP11, SP0, SP1, PARP,                      \
             JV, SV0, SV1, CTX0, CTX1, PARV, ROWB)                            \
  {                                                                           \
    float fs0 = ROWSUM(PARV, 0), fs1 = ROWSUM(PARV, 16);                      \
    float iq0 = 1.f / fs0, iq1 = 1.f / fs1;                                   \
    f32x4 pv0[4], pv1[4];                                                     \
    _Pragma("unroll")                                                         \
    for (int nt = 0; nt < 4; ++nt) {                                          \
      pv0[nt] = (f32x4){0.f, 0.f, 0.f, 0.f};                                  \
      pv1[nt] = (f32x4){0.f, 0.f, 0.f, 0.f};                                  \
    }                                                                         \
    const unsigned short* kbase = Kb + (size_t)((b * H_ + (JP)) * S_) * D_;   \
    const unsigned short* vbase =                                             \
        Vt + ((size_t)((b * H_ + (JV)) * D_) + c) * S_ + t0 + g * 8;          \
    float* wlane = w_out +                                                    \
        ((size_t)((b * H_ + i) * H_ + (JV)) * S_ + s0 + (ROWB)) * S_ + t0 +   \
        (size_t)l5 * S_ + l31 * 4;                                            \
    float rs0 = 0.f, rs1 = 0.f;                                               \
    _Pragma("unroll")                                                         \
    for (int tt = 0; tt < 8; ++tt) {                                          \
      const unsigned short* kr =                                              \
          kbase + (size_t)(t0 + tt * 16 + c) * D_ + g * 8;                    \
      short8 kf0 = *(const short8*)(kr);                                      \
      short8 kf1 = *(const short8*)(kr + 32);                                 \
      PASS1_SUB(kf0, kf1, QP00, QP01, rs0, SP0, tt)                           \
      PASS1_SUB(kf0, kf1, QP10, QP11, rs1, SP1, tt)                           \
      if (tt & 1) {                                                           \
        PVS_CHUNK(tt >> 1, SV0, SV1, pv0, pv1, iq0, iq1, vbase, wlane)        \
      }                                                                       \
    }                                                                         \
    rs0 += __shfl_xor(rs0, 16, 64);                                           \
    rs0 += __shfl_xor(rs0, 32, 64);                                           \
    rs1 += __shfl_xor(rs1, 16, 64);                                           \
    rs1 += __shfl_xor(rs1, 32, 64);                                           \
    if (lane < 16) {                                                          \
      ssum[PARP][w][lane] = rs0;                                              \
      ssum[PARP][w][16 + lane] = rs1;                                         \
    }                                                                         \
    CTX_SCALE(iq0, pv0, CTX0)                                                 \
    CTX_SCALE(iq1, pv1, CTX1)                                                 \
    asm volatile("s_waitcnt lgkmcnt(0)\n\ts_barrier" ::: "memory");           \
  }

  // ---- pipeline prologue: pass1(j=0, h0) only ----
  {
    const unsigned short* kbase = Kb + (size_t)((b * H_ + 0) * S_) * D_;
    float rs0 = 0.f, rs1 = 0.f;
#pragma unroll
    for (int tt = 0; tt < 8; ++tt) {
      const unsigned short* kr =
          kbase + (size_t)(t0 + tt * 16 + c) * D_ + g * 8;
      short8 kf0 = *(const short8*)(kr);
      short8 kf1 = *(const short8*)(kr + 32);
      PASS1_SUB(kf0, kf1, qa0, qa1, rs0, stripA, tt)
      PASS1_SUB(kf0, kf1, qb0, qb1, rs1, stripB, tt)
    }
    rs0 += __shfl_xor(rs0, 16, 64);
    rs0 += __shfl_xor(rs0, 32, 64);
    rs1 += __shfl_xor(rs1, 16, 64);
    rs1 += __shfl_xor(rs1, 32, 64);
    if (lane < 16) {
      ssum[0][w][lane] = rs0;
      ssum[0][w][16 + lane] = rs1;
    }
    asm volatile("s_waitcnt lgkmcnt(0)\n\ts_barrier" ::: "memory");
  }

  // ---- steady state: 16 slots, stores in every one ----
  for (int j = 0; j < H_; ++j) {
    // slot A: pass1(j, h1 -> C/D, par1) || PV+store(j, h0 <- A/B, par0)
    SLOT(j, qc0, qc1, qd0, qd1, stripC, stripD, 1,
         j, stripA, stripB, ctxA, ctxB, 0, 0)
    // slot B: pass1(j+1, h0 -> A/B, par0) || PV+store(j, h1 <- C/D, par1)
    // (j=7: dummy pass1 of (0,h0); nothing reads its output)
    SLOT((j + 1) & 7, qa0, qa1, qb0, qb1, stripA, stripB, 0,
         j, stripC, stripD, ctxC, ctxD, 1, 32)
  }
#undef SLOT
#undef CTX_SCALE
#undef ROWSUM
#undef PVS_CHUNK
#undef PASS1_SUB

  // ---- cross-wave ctx reduce (reuses pstrips) ----
  __syncthreads();
  float (*ctile)[64][68] = (float(*)[64][68])pstrips;   // [eighth][row][d]
#pragma unroll
  for (int nt = 0; nt < 4; ++nt)
#pragma unroll
    for (int r = 0; r < 4; ++r) {
      ctile[w][4 * g + r][nt * 16 + c]      = ctxA[nt][r];
      ctile[w][16 + 4 * g + r][nt * 16 + c] = ctxB[nt][r];
      ctile[w][32 + 4 * g + r][nt * 16 + c] = ctxC[nt][r];
      ctile[w][48 + 4 * g + r][nt * 16 + c] = ctxD[nt][r];
    }
  __syncthreads();
#pragma unroll
  for (int it = 0; it < 2; ++it) {
    const int slot = it * 512 + tid;
    const int r  = slot >> 4;          // 0..63
    const int d0 = (slot & 15) * 4;
    f32x4 s = *(const f32x4*)&ctile[0][r][d0];
#pragma unroll
    for (int e = 1; e < 8; ++e) s += *(const f32x4*)&ctile[e][r][d0];
    *(f32x4*)(ctx_out + ((size_t)(b * S_ + s0 + r) * (H_ * D_) + i * D_ + d0)) = s;
  }
}

extern "C" void kernel_launch(void* const* d_in, const int* in_sizes, int n_in,
                              void* d_out, int out_size, void* d_ws, size_t ws_size,
                              hipStream_t stream) {
  const float* Q = (const float*)d_in[0];
  const float* K = (const float*)d_in[1];
  const float* V = (const float*)d_in[2];
  // d_in[3] = valid_lens: unused by the reference.

  const size_t nelem = (size_t)B_ * H_ * S_ * D_;      // 1,048,576 per tensor
  float* outc = (float*)d_out;                          // context [B,S,H*D]
  float* outw = outc + (size_t)B_ * S_ * H_ * D_;       // weights [B,H,H,S,S]

  unsigned short* Qb = (unsigned short*)d_ws;           // 2 MB
  unsigned short* Kb = Qb + nelem;                      // 2 MB
  unsigned short* Vt = Kb + nelem;                      // 2 MB (needs ws >= 6 MB)

  prologue_kernel<<<2304, 256, 0, stream>>>(Q, K, V, Qb, Kb, Vt);
  attn_kernel<<<B_ * H_ * (S_ / 64), 512, 0, stream>>>(Qb, Kb, Vt, outw, outc);
}